// Round 3
// baseline (157.395 us; speedup 1.0000x reference)
//
#include <hip/hip_runtime.h>

// MSA conv2d-like QK correlation:
// out[b, i*3+j, h, w] = sum_c Q[b,c,h,w] * K[b,c,h+i-1,w+j-1]  (zero-padded)
// B=8, C=128, H=W=128, fp32.
//
// Round 3: C-split x4 to fix the 19%-occupancy latency bound (R2: 56us,
// 23% HBM, 2 waves/SIMD). Each block now reduces 32 channels; 4x the waves,
// 4x outstanding loads. Partials go to d_ws + float4 reduce kernel; if ws is
// too small, fall back to zero-init + atomicAdd (fp32 order noise << 0.125
// absmax tolerance).

#define Bn 8
#define Cn 128
#define Hn 128
#define Wn 128
#define HWn (Hn * Wn)
#define CSPLIT 4
#define CCHUNK (Cn / CSPLIT)
#define OUTN (Bn * 9 * HWn)  // 1179648 output elements

template <bool ATOMIC>
__global__ __launch_bounds__(256) void msa_conv_part(
    const float* __restrict__ Q, const float* __restrict__ K,
    float* __restrict__ dst) {
  const int w  = threadIdx.x;                    // 0..127
  const int h  = blockIdx.x * 2 + threadIdx.y;   // 0..127
  const int b  = blockIdx.y;                     // 0..7
  const int cs = blockIdx.z;                     // 0..3

  const bool wm  = (w > 0), wp  = (w < Wn - 1);
  const bool hmv = (h > 0), hpv = (h < Hn - 1);

  // Clamped neighbor rows/cols: OOB -> mirror to a safe in-bounds position
  // (result masked to 0 in the epilogue). Keeps the hot loop mask-free and
  // every address inside the allocation.
  const int hm = hmv ? h - 1 : h + 1;
  const int hp = hpv ? h + 1 : h - 1;
  const int dm = wm ? -1 : +1;
  const int dp = wp ? +1 : -1;

  const size_t bk = (size_t)b * Cn * HWn + (size_t)cs * CCHUNK * HWn;
  const float* q  = Q + bk + (size_t)h * Wn + w;
  const float* km = K + bk + (size_t)hm * Wn + w;
  const float* k0 = K + bk + (size_t)h  * Wn + w;
  const float* kp = K + bk + (size_t)hp * Wn + w;
  const float* kmL = km + dm; const float* kmR = km + dp;
  const float* k0L = k0 + dm; const float* k0R = k0 + dp;
  const float* kpL = kp + dm; const float* kpR = kp + dp;

  float a00 = 0.f, a01 = 0.f, a02 = 0.f;
  float a10 = 0.f, a11 = 0.f, a12 = 0.f;
  float a20 = 0.f, a21 = 0.f, a22 = 0.f;

#pragma unroll 4
  for (int c = 0; c < CCHUNK; ++c) {
    const float qv = *q;
    const float m0 = *kmL, m1 = *km, m2 = *kmR;
    const float z0 = *k0L, z1 = *k0, z2 = *k0R;
    const float p0 = *kpL, p1 = *kp, p2 = *kpR;
    a00 += qv * m0; a01 += qv * m1; a02 += qv * m2;
    a10 += qv * z0; a11 += qv * z1; a12 += qv * z2;
    a20 += qv * p0; a21 += qv * p1; a22 += qv * p2;
    q += HWn;
    km += HWn; kmL += HWn; kmR += HWn;
    k0 += HWn; k0L += HWn; k0R += HWn;
    kp += HWn; kpL += HWn; kpR += HWn;
  }

  float res[9];
  res[0] = (hmv && wm) ? a00 : 0.f;
  res[1] = hmv ? a01 : 0.f;
  res[2] = (hmv && wp) ? a02 : 0.f;
  res[3] = wm ? a10 : 0.f;
  res[4] = a11;
  res[5] = wp ? a12 : 0.f;
  res[6] = (hpv && wm) ? a20 : 0.f;
  res[7] = hpv ? a21 : 0.f;
  res[8] = (hpv && wp) ? a22 : 0.f;

  const size_t o = (size_t)b * 9 * HWn + (size_t)h * Wn + w;
  if (ATOMIC) {
#pragma unroll
    for (int t = 0; t < 9; ++t)
      atomicAdd(dst + o + (size_t)t * HWn, res[t]);
  } else {
    float* p = dst + (size_t)cs * OUTN + o;
#pragma unroll
    for (int t = 0; t < 9; ++t) {
      *p = res[t];
      p += HWn;
    }
  }
}

// Sum the 4 C-chunk partials: out[i] = sum_cs ws[cs*OUTN + i], float4-wide.
__global__ __launch_bounds__(256) void msa_reduce4(
    const float* __restrict__ part, float* __restrict__ out) {
  const int i = blockIdx.x * 256 + threadIdx.x;  // float4 index, OUTN/4 total
  const float4* p = (const float4*)part;
  const int n4 = OUTN / 4;
  float4 s0 = p[i];
  float4 s1 = p[n4 + i];
  float4 s2 = p[2 * n4 + i];
  float4 s3 = p[3 * n4 + i];
  float4 r;
  r.x = (s0.x + s1.x) + (s2.x + s3.x);
  r.y = (s0.y + s1.y) + (s2.y + s3.y);
  r.z = (s0.z + s1.z) + (s2.z + s3.z);
  r.w = (s0.w + s1.w) + (s2.w + s3.w);
  ((float4*)out)[i] = r;
}

__global__ __launch_bounds__(256) void msa_zero(float* __restrict__ out) {
  const int i = blockIdx.x * 256 + threadIdx.x;
  ((float4*)out)[i] = make_float4(0.f, 0.f, 0.f, 0.f);
}

extern "C" void kernel_launch(void* const* d_in, const int* in_sizes, int n_in,
                              void* d_out, int out_size, void* d_ws,
                              size_t ws_size, hipStream_t stream) {
  const float* Q = (const float*)d_in[0];
  const float* K = (const float*)d_in[1];
  float* out = (float*)d_out;

  dim3 block(128, 2);
  dim3 grid(Hn / 2, Bn, CSPLIT);  // 64 x 8 x 4 = 2048 blocks = 8192 waves

  const size_t ws_need = (size_t)CSPLIT * OUTN * sizeof(float);  // 18.9 MB
  if (ws_size >= ws_need) {
    float* part = (float*)d_ws;
    msa_conv_part<false><<<grid, block, 0, stream>>>(Q, K, part);
    msa_reduce4<<<OUTN / 4 / 256, 256, 0, stream>>>(part, out);
  } else {
    msa_zero<<<OUTN / 4 / 256, 256, 0, stream>>>(out);
    msa_conv_part<true><<<grid, block, 0, stream>>>(Q, K, out);
  }
}

// Round 4
// 154.686 us; speedup vs baseline: 1.0175x; 1.0175x over previous
//
#include <hip/hip_runtime.h>

// MSA conv2d-like QK correlation:
// out[b, i*3+j, h, w] = sum_c Q[b,c,h,w] * K[b,c,h+i-1,w+j-1]  (zero-padded)
// B=8, C=128, H=W=128, fp32.
//
// Round 4: R3 showed time invariant to occupancy (19->35%, both ~56us, HBM
// 26%, VALU 17%) -> bound by L1/TA address processing: 10 scalar wave-loads
// per c-iter, 6 of them line-crossing (2x TA cost), K re-read 9x through L1.
// Fix: float4 per thread (aligned dwordx4 only: Q + 3 K rows), column taps
// from registers + __shfl(+-1 lane); edge-garbage components are exactly the
// ones the epilogue masks to zero. VMEM instrs/c-iter: 10 -> 4, all aligned,
// 4x bytes each. C-split x4 with ws partials + float4 reduce (atomic
// fallback if ws too small).

#define Bn 8
#define Cn 128
#define Hn 128
#define Wn 128
#define HWn (Hn * Wn)
#define CSPLIT 4
#define CCHUNK (Cn / CSPLIT)
#define OUTN (Bn * 9 * HWn)  // 1179648 output elements

template <bool ATOMIC>
__global__ __launch_bounds__(256) void msa_conv_v4(
    const float* __restrict__ Q, const float* __restrict__ K,
    float* __restrict__ dst) {
  const int tid  = threadIdx.x;
  const int lane = tid & 63;
  const int wq   = lane & 31;  // float4 column index; w0 = 4*wq in 0..124
  const int rl   = lane >> 5;  // row-within-wave (wave covers 2 rows x 128 w)
  const int wv   = tid >> 6;   // wave id 0..3 -> block covers 8 rows
  const int h0   = blockIdx.x * 8;
  const int r    = h0 + wv * 2 + rl;  // output row 0..127
  const int b    = blockIdx.y;
  const int cs   = blockIdx.z;
  const int w0   = wq * 4;

  // Row-clamped neighbor rows (OOB rows mirrored in-bounds; their taps are
  // zeroed in the epilogue). All global addresses stay inside the (b,c) slice.
  const int rm = (r > 0) ? r - 1 : r + 1;
  const int rp = (r < Hn - 1) ? r + 1 : r - 1;

  const size_t base = (size_t)b * Cn * HWn + (size_t)cs * CCHUNK * HWn;
  const float* qp = Q + base + (size_t)r  * Wn + w0;
  const float* mp = K + base + (size_t)rm * Wn + w0;
  const float* zp = K + base + (size_t)r  * Wn + w0;
  const float* pp = K + base + (size_t)rp * Wn + w0;

  float acc[9][4];
#pragma unroll
  for (int t = 0; t < 9; ++t)
#pragma unroll
    for (int k = 0; k < 4; ++k) acc[t][k] = 0.f;

  // acc[t][k] += Q[w0+k] * K_row[w0+k+j]; j=-1 uses (L,x,y,z), j=0 (x,y,z,w),
  // j=+1 (y,z,w,R) where L/R are shuffled-in neighbor-lane elements.
#define ACC4(t, s0, s1, s2, s3) \
  acc[t][0] += q4.x * (s0);     \
  acc[t][1] += q4.y * (s1);     \
  acc[t][2] += q4.z * (s2);     \
  acc[t][3] += q4.w * (s3);

#pragma unroll 2
  for (int c = 0; c < CCHUNK; ++c) {
    const float4 q4 = *(const float4*)qp;
    const float4 m4 = *(const float4*)mp;
    const float4 z4 = *(const float4*)zp;
    const float4 p4 = *(const float4*)pp;
    // Left neighbor element K[row][w0-1] = lane-1's .w; right K[row][w0+4] =
    // lane+1's .x. Lane 0/32 (wq==0) and lane 31/63 (wq==31) receive garbage
    // (cross-row or clamped) -- exactly the components masked below.
    const float mL = __shfl_up(m4.w, 1, 64);
    const float zL = __shfl_up(z4.w, 1, 64);
    const float pL = __shfl_up(p4.w, 1, 64);
    const float mR = __shfl_down(m4.x, 1, 64);
    const float zR = __shfl_down(z4.x, 1, 64);
    const float pR = __shfl_down(p4.x, 1, 64);

    ACC4(0, mL,   m4.x, m4.y, m4.z)   // i=-1, j=-1
    ACC4(1, m4.x, m4.y, m4.z, m4.w)   // i=-1, j= 0
    ACC4(2, m4.y, m4.z, m4.w, mR)     // i=-1, j=+1
    ACC4(3, zL,   z4.x, z4.y, z4.z)   // i= 0, j=-1
    ACC4(4, z4.x, z4.y, z4.z, z4.w)   // i= 0, j= 0
    ACC4(5, z4.y, z4.z, z4.w, zR)     // i= 0, j=+1
    ACC4(6, pL,   p4.x, p4.y, p4.z)   // i=+1, j=-1
    ACC4(7, p4.x, p4.y, p4.z, p4.w)   // i=+1, j= 0
    ACC4(8, p4.y, p4.z, p4.w, pR)     // i=+1, j=+1

    qp += HWn; mp += HWn; zp += HWn; pp += HWn;
  }
#undef ACC4

  // Epilogue masking: OOB taps/components have fully-zero C-sums in the
  // reference (zero padding), so zero them here.
  if (wq == 0)  { acc[0][0] = 0.f; acc[3][0] = 0.f; acc[6][0] = 0.f; }
  if (wq == 31) { acc[2][3] = 0.f; acc[5][3] = 0.f; acc[8][3] = 0.f; }
  if (r == 0) {
#pragma unroll
    for (int t = 0; t < 3; ++t)
#pragma unroll
      for (int k = 0; k < 4; ++k) acc[t][k] = 0.f;
  }
  if (r == Hn - 1) {
#pragma unroll
    for (int t = 6; t < 9; ++t)
#pragma unroll
      for (int k = 0; k < 4; ++k) acc[t][k] = 0.f;
  }

  const size_t o = (size_t)b * 9 * HWn + (size_t)r * Wn + w0;
  if (ATOMIC) {
#pragma unroll
    for (int t = 0; t < 9; ++t)
#pragma unroll
      for (int k = 0; k < 4; ++k)
        atomicAdd(dst + o + (size_t)t * HWn + k, acc[t][k]);
  } else {
    float* p = dst + (size_t)cs * OUTN + o;
#pragma unroll
    for (int t = 0; t < 9; ++t) {
      *(float4*)(p + (size_t)t * HWn) =
          make_float4(acc[t][0], acc[t][1], acc[t][2], acc[t][3]);
    }
  }
}

// Sum the 4 C-chunk partials: out[i] = sum_cs ws[cs*OUTN + i], float4-wide.
__global__ __launch_bounds__(256) void msa_reduce4(
    const float* __restrict__ part, float* __restrict__ out) {
  const int i = blockIdx.x * 256 + threadIdx.x;  // float4 index
  const float4* p = (const float4*)part;
  const int n4 = OUTN / 4;
  float4 s0 = p[i];
  float4 s1 = p[n4 + i];
  float4 s2 = p[2 * n4 + i];
  float4 s3 = p[3 * n4 + i];
  float4 r;
  r.x = (s0.x + s1.x) + (s2.x + s3.x);
  r.y = (s0.y + s1.y) + (s2.y + s3.y);
  r.z = (s0.z + s1.z) + (s2.z + s3.z);
  r.w = (s0.w + s1.w) + (s2.w + s3.w);
  ((float4*)out)[i] = r;
}

__global__ __launch_bounds__(256) void msa_zero(float* __restrict__ out) {
  const int i = blockIdx.x * 256 + threadIdx.x;
  ((float4*)out)[i] = make_float4(0.f, 0.f, 0.f, 0.f);
}

extern "C" void kernel_launch(void* const* d_in, const int* in_sizes, int n_in,
                              void* d_out, int out_size, void* d_ws,
                              size_t ws_size, hipStream_t stream) {
  const float* Q = (const float*)d_in[0];
  const float* K = (const float*)d_in[1];
  float* out = (float*)d_out;

  dim3 block(256);
  dim3 grid(Hn / 8, Bn, CSPLIT);  // 16 x 8 x 4 = 512 blocks, 2048 waves

  const size_t ws_need = (size_t)CSPLIT * OUTN * sizeof(float);  // 18.9 MB
  if (ws_size >= ws_need) {
    float* part = (float*)d_ws;
    msa_conv_v4<false><<<grid, block, 0, stream>>>(Q, K, part);
    msa_reduce4<<<OUTN / 4 / 256, 256, 0, stream>>>(part, out);
  } else {
    msa_zero<<<OUTN / 4 / 256, 256, 0, stream>>>(out);
    msa_conv_v4<true><<<grid, block, 0, stream>>>(Q, K, out);
  }
}

// Round 5
// 154.401 us; speedup vs baseline: 1.0194x; 1.0018x over previous
//
#include <hip/hip_runtime.h>

// MSA conv2d-like QK correlation:
// out[b, i*3+j, h, w] = sum_c Q[b,c,h,w] * K[b,c,h+i-1,w+j-1]  (zero-padded)
// B=8, C=128, H=W=128, fp32.
//
// Round 5: R2/R3/R4 all ~55us with every counter idle -> effective read rate
// pinned at ~2.4 TB/s regardless of wave count or VMEM instr count. Theory:
// per-wave load pipeline too shallow (VGPR-starved) -> latency-bound.
// Discriminating fix: global_load_lds async K staging (deep DMA queue, no
// VGPR cost) + Q register prefetch one chunk ahead + counted-vmcnt pipeline
// (m201 pattern: loads stay in flight across raw s_barrier).
//
// Geometry: block = 256 thr = 4 waves, owns (b, rows r0..r0+3, all 128 w).
// Waves 0-1: c 0..63; waves 2-3: c 64..127 (same pixels) -> LDS reduce.
// Per c-slice K rows r0-1..r0+4 (6 rows, 3KB, globally contiguous) staged to
// LDS once; taps read from LDS at 4B alignment (no shuffles, no K re-read).
// Grid 8x32 = 256 blocks (1/CU). LDS 48KB static double buffer.

#define Bn 8
#define Cn 128
#define Hn 128
#define Wn 128
#define HWn (Hn * Wn)
#define TC 4              // c-slices per chunk per half
#define NCHUNK (64 / TC)  // 16 chunks per half

__device__ __forceinline__ void async16(void* lds, const void* g) {
  __builtin_amdgcn_global_load_lds(
      (const __attribute__((address_space(1))) void*)g,
      (__attribute__((address_space(3))) void*)lds, 16, 0, 0);
}

__global__ __launch_bounds__(256) void msa_conv_v5(
    const float* __restrict__ Q, const float* __restrict__ K,
    float* __restrict__ out) {
  // [buf][step][half][row 0..5][w 0..127] : 2*4*2*6*512B = 48 KB
  __shared__ float kbuf[2][TC][2][6][Wn];

  const int tid  = threadIdx.x;
  const int lane = tid & 63;
  const int wv   = tid >> 6;   // wave 0..3
  const int hh   = wv >> 1;    // c-half owned by this wave
  const int qpar = wv & 1;     // staging parity within the half
  const int idx  = tid & 127;  // pixel index within tile (two threads/pixel)
  const int rr   = idx >> 5;   // row 0..3 within tile
  const int wq   = idx & 31;   // float4 column
  const int w0   = wq * 4;
  const int r0   = blockIdx.x * 4;
  const int r    = r0 + rr;
  const int b    = blockIdx.y;

  // Staged K rows are global rows src0..src0+5 (always in-bounds).
  const int src0 = (r0 == 0) ? 0 : ((r0 == Hn - 4) ? (Hn - 6) : (r0 - 1));
  // Mirror-clamped neighbor rows (mirrored rows are inside the staged range;
  // their taps are zeroed in the epilogue).
  const int rm = (r > 0) ? r - 1 : r + 1;
  const int rp = (r < Hn - 1) ? r + 1 : r - 1;
  const int sm = rm - src0, s0 = r - src0, sp = rp - src0;

  // Byte offsets within a 512B LDS K-row for center/left/right taps.
  // Edge threads read a clamped in-row slot (garbage, masked in epilogue).
  const int offc = w0 * 4;
  const int offl = (wq == 0) ? 0 : (offc - 4);
  const int offr = (wq == 31) ? (offc + 12) : (offc + 16);

  const char* kbytes = (const char*)K + (size_t)b * Cn * HWn * 4;
  char* lds0 = (char*)&kbuf[0][0][0][0][0];
  const float* qbase =
      Q + ((size_t)b * Cn + (size_t)hh * 64) * HWn + (size_t)r * Wn + w0;

  float acc[9][4] = {};
  float4 qA[TC], qB[TC];

  // This wave stages steps {qpar, qpar+2} of its half: 6 async16 per chunk.
#define STAGE(chn, bufn)                                                     \
  do {                                                                       \
    _Pragma("unroll") for (int j = 0; j < 2; ++j) {                          \
      const int s = qpar + 2 * j;                                            \
      const int c = hh * 64 + (chn) * TC + s;                                \
      const char* src =                                                      \
          kbytes + (size_t)c * (HWn * 4) + src0 * 512 + lane * 16;           \
      char* dst = lds0 + (((bufn) * TC + s) * 2 + hh) * 3072 + lane * 16;    \
      async16(dst, src);                                                     \
      async16(dst + 1024, src + 1024);                                       \
      async16(dst + 2048, src + 2048);                                       \
    }                                                                        \
  } while (0)

#define LOADQ(dst, chn)                                                      \
  do {                                                                       \
    const float* qp = qbase + (size_t)(chn) * TC * HWn;                      \
    _Pragma("unroll") for (int s = 0; s < TC; ++s) dst[s] =                  \
        *(const float4*)(qp + (size_t)s * HWn);                              \
  } while (0)

#define ROW(t0, rb)                                                          \
  do {                                                                       \
    const float4 kc = *(const float4*)((rb) + offc);                         \
    const float kl = *(const float*)((rb) + offl);                           \
    const float kr = *(const float*)((rb) + offr);                           \
    acc[t0][0] += qv.x * kl;                                                 \
    acc[t0][1] += qv.y * kc.x;                                               \
    acc[t0][2] += qv.z * kc.y;                                               \
    acc[t0][3] += qv.w * kc.z;                                               \
    acc[t0 + 1][0] += qv.x * kc.x;                                           \
    acc[t0 + 1][1] += qv.y * kc.y;                                           \
    acc[t0 + 1][2] += qv.z * kc.z;                                           \
    acc[t0 + 1][3] += qv.w * kc.w;                                           \
    acc[t0 + 2][0] += qv.x * kc.y;                                           \
    acc[t0 + 2][1] += qv.y * kc.z;                                           \
    acc[t0 + 2][2] += qv.z * kc.w;                                           \
    acc[t0 + 2][3] += qv.w * kr;                                             \
  } while (0)

#define COMPUTE(qreg, bufn)                                                  \
  do {                                                                       \
    _Pragma("unroll") for (int s = 0; s < TC; ++s) {                         \
      const char* kstep = lds0 + (((bufn) * TC + s) * 2 + hh) * 3072;        \
      const float4 qv = qreg[s];                                             \
      ROW(0, kstep + sm * 512);                                              \
      ROW(3, kstep + s0 * 512);                                              \
      ROW(6, kstep + sp * 512);                                              \
    }                                                                        \
  } while (0)

  // Prologue: chunk 0 in flight.
  LOADQ(qA, 0);
  asm volatile("" ::: "memory");
  STAGE(0, 0);
  asm volatile("" ::: "memory");

#pragma unroll 1
  for (int ch = 0; ch < NCHUNK; ch += 2) {
    // Even chunk: compute buf0/qA; prefetch chunk ch+1 into buf1/qB.
    LOADQ(qB, ch + 1);
    asm volatile("" ::: "memory");
    STAGE(ch + 1, 1);
    // Outstanding (this wave): [qA(4),K_ch(6)] older, [qB(4),K_next(6)] newer.
    // vmcnt(10) -> qA and K_ch landed; next chunk's 10 stay in flight.
    asm volatile("s_waitcnt vmcnt(10)" ::: "memory");
    __builtin_amdgcn_s_barrier();
    asm volatile("" ::: "memory");
    COMPUTE(qA, 0);
    asm volatile("" ::: "memory");
    __builtin_amdgcn_s_barrier();  // all reads of buf0 done before restage

    // Odd chunk: compute buf1/qB; prefetch chunk ch+2 into buf0/qA.
    if (ch + 2 < NCHUNK) {
      LOADQ(qA, ch + 2);
      asm volatile("" ::: "memory");
      STAGE(ch + 2, 0);
      asm volatile("s_waitcnt vmcnt(10)" ::: "memory");
    } else {
      asm volatile("s_waitcnt vmcnt(0)" ::: "memory");
    }
    __builtin_amdgcn_s_barrier();
    asm volatile("" ::: "memory");
    COMPUTE(qB, 1);
    asm volatile("" ::: "memory");
    __builtin_amdgcn_s_barrier();
  }

  // Cross-half reduction: half 1 parks its partials in LDS (reuse kbuf).
  __syncthreads();
  float* scr = (float*)lds0;  // 128 pixels * 36 floats = 18 KB
  if (hh == 1) {
#pragma unroll
    for (int t = 0; t < 9; ++t)
#pragma unroll
      for (int k = 0; k < 4; ++k) scr[idx * 36 + t * 4 + k] = acc[t][k];
  }
  __syncthreads();
  if (hh == 0) {
#pragma unroll
    for (int t = 0; t < 9; ++t)
#pragma unroll
      for (int k = 0; k < 4; ++k) acc[t][k] += scr[idx * 36 + t * 4 + k];

    // Epilogue masking: OOB taps have fully-zero C-sums (zero padding).
    if (wq == 0) { acc[0][0] = 0.f; acc[3][0] = 0.f; acc[6][0] = 0.f; }
    if (wq == 31) { acc[2][3] = 0.f; acc[5][3] = 0.f; acc[8][3] = 0.f; }
    if (r == 0) {
#pragma unroll
      for (int t = 0; t < 3; ++t)
#pragma unroll
        for (int k = 0; k < 4; ++k) acc[t][k] = 0.f;
    }
    if (r == Hn - 1) {
#pragma unroll
      for (int t = 6; t < 9; ++t)
#pragma unroll
        for (int k = 0; k < 4; ++k) acc[t][k] = 0.f;
    }

    float* o = out + (size_t)b * 9 * HWn + (size_t)r * Wn + w0;
#pragma unroll
    for (int t = 0; t < 9; ++t)
      *(float4*)(o + (size_t)t * HWn) =
          make_float4(acc[t][0], acc[t][1], acc[t][2], acc[t][3]);
  }
}

extern "C" void kernel_launch(void* const* d_in, const int* in_sizes, int n_in,
                              void* d_out, int out_size, void* d_ws,
                              size_t ws_size, hipStream_t stream) {
  const float* Q = (const float*)d_in[0];
  const float* K = (const float*)d_in[1];
  float* out = (float*)d_out;

  dim3 block(256);
  dim3 grid(Hn / 4, Bn);  // 32 x 8 = 256 blocks
  msa_conv_v5<<<grid, block, 0, stream>>>(Q, K, out);
}